// Round 8
// baseline (2488.728 us; speedup 1.0000x reference)
//
#include <hip/hip_runtime.h>
#include <stdint.h>

#define BATCH 64
#define F_ENC 2048
#define HID 8192
#define NCLS 100
#define NMAT 6
#define NSP (NMAT * HID)   // 49152 sparsify blocks
#define B_PACK 8
#define NB_L1 32
#define NB_L2 32
#define NB_LOG 256

// counter indices (in ws, zeroed by hipMemsetAsync before launch)
#define C_M0 0   // ..C_M5 = 5: per-matrix completed-block counts (target 8192)
#define C_PACK 6 // target 8
#define C_L1 7   // target 32
#define C_L2 8   // target 32

typedef unsigned long long ull;
typedef uint32_t u32x4 __attribute__((ext_vector_type(4)));

// ---------------------------------------------------------------------------
__device__ __forceinline__ void publish(uint32_t* cnt, int idx) {
  __syncthreads();
  if (threadIdx.x == 0) {
    __threadfence();
    atomicAdd(&cnt[idx], 1u);
  }
}

__device__ __forceinline__ void wait3(uint32_t* cnt, int i0, uint32_t t0,
                                      int i1, uint32_t t1, int i2,
                                      uint32_t t2) {
  if (threadIdx.x == 0) {
    while (__hip_atomic_load(&cnt[i0], __ATOMIC_ACQUIRE,
                             __HIP_MEMORY_SCOPE_AGENT) < t0 ||
           __hip_atomic_load(&cnt[i1], __ATOMIC_ACQUIRE,
                             __HIP_MEMORY_SCOPE_AGENT) < t1 ||
           __hip_atomic_load(&cnt[i2], __ATOMIC_ACQUIRE,
                             __HIP_MEMORY_SCOPE_AGENT) < t2)
      __builtin_amdgcn_s_sleep(8);
  }
  __syncthreads();
}

// ---------------------------------------------------------------------------
__device__ __forceinline__ void scan_vec(u32x4 w, int vecIdx,
                                         unsigned* s_cnt, uint16_t* s_ent) {
  uint32_t vals[4] = {w[0], w[1], w[2], w[3]};
#pragma unroll
  for (int e = 0; e < 4; ++e) {
    uint32_t u = vals[e];
    if (u != 0u) {  // value is exactly +1.0f or -1.0f
      unsigned slot = atomicAdd(s_cnt, 1u);
      s_ent[slot & 15u] = (uint16_t)(((vecIdx << 2) + e) | ((u >> 31) << 15));
    }
  }
}

// ---------------------------------------------------------------------------
// Bit-sliced 4-bit counters over the 64-batch bitmask lanes.
// ---------------------------------------------------------------------------
struct BS4 { ull p0, p1, p2, p3; };

__device__ __forceinline__ void bs_add(BS4& a, ull m) {
  ull c = m, t;
  t = a.p0 ^ c; c &= a.p0; a.p0 = t;
  t = a.p1 ^ c; c &= a.p1; a.p1 = t;
  t = a.p2 ^ c; c &= a.p2; a.p2 = t;
  a.p3 ^= c;  // count <= 8, no overflow
}

__device__ __forceinline__ ull bs_fired(const BS4& A, const BS4& Mn) {
  ull b0 = Mn.p0, b1 = Mn.p1;
  ull carry = Mn.p2;
  ull b2 = ~Mn.p2;
  ull b3 = Mn.p3 ^ carry;
  ull b4 = Mn.p3 & carry;
  ull res = 0, eq = ~0ull;
  eq &= ~b4;  // a4 == 0
  res |= eq & A.p3 & ~b3; eq &= ~(A.p3 ^ b3);
  res |= eq & A.p2 & ~b2; eq &= ~(A.p2 ^ b2);
  res |= eq & A.p1 & ~b1; eq &= ~(A.p1 ^ b1);
  res |= eq & A.p0 & ~b0; eq &= ~(A.p0 ^ b0);
  return res | eq;
}

__device__ __forceinline__ ull layer_fire(const uint16_t* __restrict__ ent0,
                                          const uint16_t* __restrict__ ent1,
                                          const ull* __restrict__ Aprev,
                                          int h) {
  uint4 p0 = ((const uint4*)ent0)[h];
  uint4 p1 = ((const uint4*)ent1)[h];
  uint32_t wd[8] = {p0.x, p0.y, p0.z, p0.w, p1.x, p1.y, p1.z, p1.w};
  uint16_t es[16];
#pragma unroll
  for (int i = 0; i < 8; ++i) {
    es[2 * i]     = (uint16_t)(wd[i] & 0xFFFFu);
    es[2 * i + 1] = (uint16_t)(wd[i] >> 16);
  }
  ull M[16];
#pragma unroll
  for (int i = 0; i < 16; ++i) {
    int idx = (es[i] == 0xFFFF) ? 0 : (es[i] & 0x1FFF);
    ull v = Aprev[idx];
    M[i] = (es[i] == 0xFFFF) ? 0ull : v;
  }
  ull f = 0;
#pragma unroll
  for (int s = 0; s < 2; ++s) {
    BS4 P{0, 0, 0, 0}, N{0, 0, 0, 0};
#pragma unroll
    for (int i = 0; i < 8; ++i) {
      uint16_t e = es[s * 8 + i];
      ull Mm = M[s * 8 + i];
      ull mp = (e & 0x8000) ? 0ull : Mm;
      ull mn = (e & 0x8000) ? Mm : 0ull;
      bs_add(P, mp);
      bs_add(N, mn);
    }
    f |= bs_fired(P, N);
  }
  return f;
}

// ---------------------------------------------------------------------------
// Mega-kernel: pack | sparsify-stream | layer1 | layer2 | layer3+logits,
// pipelined via device-scope counters. Consumer blocks sit at the END of
// the grid; correctness does not depend on dispatch order (they wait on
// data counters), and 320 consumers << 1536 resident-block slots, so
// producers can never be starved (no deadlock).
// ---------------------------------------------------------------------------
__global__ void __launch_bounds__(256) mega_kernel(
    const uint32_t* __restrict__ W0a, const uint32_t* __restrict__ W0b,
    const uint32_t* __restrict__ W1a, const uint32_t* __restrict__ W1b,
    const uint32_t* __restrict__ W2a, const uint32_t* __restrict__ W2b,
    const float* __restrict__ x,
    const float* __restrict__ O0, const float* __restrict__ O1,
    const float* __restrict__ O2,
    ull* __restrict__ A0, ull* __restrict__ A1, ull* __restrict__ A2,
    uint16_t* __restrict__ entries, uint32_t* __restrict__ cnt,
    float* __restrict__ out) {
  __shared__ float acc[BATCH * NCLS];  // 25.6 KB (logits phase)
  __shared__ ull sA3[32];
  __shared__ unsigned s_cnt;
  __shared__ uint16_t s_ent[16];

  const uint32_t bid = blockIdx.x;

  // ---------------- pack: binarize x -> per-column batch masks ----------------
  if (bid < B_PACK) {
    int c = bid * 256 + threadIdx.x;
    ull m = 0;
#pragma unroll
    for (int b = 0; b < BATCH; ++b)
      m |= (ull)(x[(size_t)b * F_ENC + c] > 0.5f) << b;
    A0[c] = m;
    publish(cnt, C_PACK);
    return;
  }

  // ---------------- sparsify: the 1.208 GB stream (proven roofline) ----------
  if (bid < B_PACK + NSP) {
    int blk = bid - B_PACK;
    int m = blk >> 13;               // which matrix (0..5)
    int r = blk & (HID - 1);         // row within matrix
    const uint32_t* Wbase;
    switch (m) {
      case 0: Wbase = W0a; break;
      case 1: Wbase = W0b; break;
      case 2: Wbase = W1a; break;
      case 3: Wbase = W1b; break;
      case 4: Wbase = W2a; break;
      default: Wbase = W2b; break;
    }
    const int cols = (m < 2) ? F_ENC : HID;
    const u32x4* row = (const u32x4*)(Wbase + (size_t)r * cols);

    if (threadIdx.x == 0) s_cnt = 0u;
    __syncthreads();

    if (cols == F_ENC) {
      u32x4 w0 = __builtin_nontemporal_load(row + threadIdx.x);
      u32x4 w1 = __builtin_nontemporal_load(row + threadIdx.x + 256);
      asm volatile("" ::: "memory");
      uint32_t any = w0[0] | w0[1] | w0[2] | w0[3] |
                     w1[0] | w1[1] | w1[2] | w1[3];
      if (any) {
        scan_vec(w0, threadIdx.x, &s_cnt, s_ent);
        scan_vec(w1, threadIdx.x + 256, &s_cnt, s_ent);
      }
    } else {
      u32x4 w[8];
#pragma unroll
      for (int e = 0; e < 8; ++e)
        w[e] = __builtin_nontemporal_load(row + threadIdx.x + (e << 8));
      asm volatile("" ::: "memory");
      uint32_t any = 0;
#pragma unroll
      for (int e = 0; e < 8; ++e) any |= w[e][0] | w[e][1] | w[e][2] | w[e][3];
      if (any) {
#pragma unroll
        for (int e = 0; e < 8; ++e)
          scan_vec(w[e], threadIdx.x + (e << 8), &s_cnt, s_ent);
      }
    }
    __syncthreads();
    if (threadIdx.x < 8) {
      unsigned c = s_cnt;
      uint16_t v = (threadIdx.x < c) ? s_ent[threadIdx.x] : (uint16_t)0xFFFF;
      entries[(size_t)blk * 8 + threadIdx.x] = v;
    }
    publish(cnt, m);
    return;
  }

  // ---------------- layer 1 (32 blocks): waits pack + mats 0,1 ---------------
  if (bid < B_PACK + NSP + NB_L1) {
    int lb = bid - (B_PACK + NSP);
    wait3(cnt, C_PACK, B_PACK, C_M0 + 0, HID, C_M0 + 1, HID);
    int h = lb * 256 + threadIdx.x;
    A1[h] = layer_fire(entries + (size_t)0 * HID * 8,
                       entries + (size_t)1 * HID * 8, A0, h);
    publish(cnt, C_L1);
    return;
  }

  // ---------------- layer 2 (32 blocks): waits layer1 + mats 2,3 -------------
  if (bid < B_PACK + NSP + NB_L1 + NB_L2) {
    int lb = bid - (B_PACK + NSP + NB_L1);
    wait3(cnt, C_L1, NB_L1, C_M0 + 2, HID, C_M0 + 3, HID);
    int h = lb * 256 + threadIdx.x;
    A2[h] = layer_fire(entries + (size_t)2 * HID * 8,
                       entries + (size_t)3 * HID * 8, A1, h);
    publish(cnt, C_L2);
    return;
  }

  // ---------------- layer3 + logits (256 blocks): waits layer2 + mats 4,5 ----
  {
    int lb = bid - (B_PACK + NSP + NB_L1 + NB_L2);
    wait3(cnt, C_L2, NB_L2, C_M0 + 4, HID, C_M0 + 5, HID);
    const int h0 = lb * 32;
    if (threadIdx.x < 32)
      sA3[threadIdx.x] = layer_fire(entries + (size_t)4 * HID * 8,
                                    entries + (size_t)5 * HID * 8, A2,
                                    h0 + threadIdx.x);
    for (int i = threadIdx.x; i < BATCH * NCLS; i += 256) acc[i] = 0.f;
    __syncthreads();
    const int half = threadIdx.x >> 7;  // 0: batches 0-31, 1: batches 32-63
    const int j = threadIdx.x & 127;
    if (j < NCLS) {
      const int bofs = half * 32;
      const int sh = half * 32;
      for (int k = 0; k < 32; ++k) {
        int h = h0 + k;
        uint32_t m1 = (uint32_t)(A1[h] >> sh);
        uint32_t m2 = (uint32_t)(A2[h] >> sh);
        uint32_t m3 = (uint32_t)(sA3[k] >> sh);
        if (m1) {
          float o = O0[(size_t)h * NCLS + j];
          do { int b = __builtin_ctz(m1); m1 &= m1 - 1; acc[(b + bofs) * NCLS + j] += o; } while (m1);
        }
        if (m2) {
          float o = O1[(size_t)h * NCLS + j];
          do { int b = __builtin_ctz(m2); m2 &= m2 - 1; acc[(b + bofs) * NCLS + j] += o; } while (m2);
        }
        if (m3) {
          float o = O2[(size_t)h * NCLS + j];
          do { int b = __builtin_ctz(m3); m3 &= m3 - 1; acc[(b + bofs) * NCLS + j] += o; } while (m3);
        }
      }
    }
    __syncthreads();
    for (int i = threadIdx.x; i < BATCH * NCLS; i += 256)
      atomicAdd(&out[i], acc[i]);
  }
}

// ---------------------------------------------------------------------------
extern "C" void kernel_launch(void* const* d_in, const int* in_sizes, int n_in,
                              void* d_out, int out_size, void* d_ws, size_t ws_size,
                              hipStream_t stream) {
  const float*    x   = (const float*)d_in[0];
  const uint32_t* W0a = (const uint32_t*)d_in[1];
  const uint32_t* W0b = (const uint32_t*)d_in[2];
  const uint32_t* W1a = (const uint32_t*)d_in[3];
  const uint32_t* W1b = (const uint32_t*)d_in[4];
  const uint32_t* W2a = (const uint32_t*)d_in[5];
  const uint32_t* W2b = (const uint32_t*)d_in[6];
  const float*    O0  = (const float*)d_in[7];
  const float*    O1  = (const float*)d_in[8];
  const float*    O2  = (const float*)d_in[9];
  float* out = (float*)d_out;
  char*  ws  = (char*)d_ws;

  // ws layout:
  ull* A0 = (ull*)(ws);                          // 16384 B
  ull* A1 = (ull*)(ws + 16384);                  // 65536 B
  ull* A2 = (ull*)(ws + 16384 + 65536);          // 65536 B
  uint16_t* entries = (uint16_t*)(ws + 16384 + 2 * 65536);  // 786432 B
  uint32_t* cnt = (uint32_t*)(ws + 16384 + 2 * 65536 + 786432);  // 64 B

  hipMemsetAsync(cnt, 0, 64, stream);
  hipMemsetAsync(out, 0, BATCH * NCLS * sizeof(float), stream);

  mega_kernel<<<B_PACK + NSP + NB_L1 + NB_L2 + NB_LOG, 256, 0, stream>>>(
      W0a, W0b, W1a, W1b, W2a, W2b, x, O0, O1, O2, A0, A1, A2, entries, cnt,
      out);
}

// Round 9
// 305.460 us; speedup vs baseline: 8.1475x; 8.1475x over previous
//
#include <hip/hip_runtime.h>
#include <stdint.h>

#define BATCH 64
#define F_ENC 2048
#define HID 8192
#define NCLS 100
#define NMAT 6
#define EXTRA 9  // 8 pack blocks + 1 out-zero block, prepended so they run first

typedef unsigned long long ull;
typedef uint32_t u32x4 __attribute__((ext_vector_type(4)));

// ---------------------------------------------------------------------------
// Kernel 1 (UNCHANGED from R7, proven 196 us = read roofline): sparsify with
// pack + d_out zeroing fused in as EXTRA leading blocks.
// Entry: uint16 = col (13b) | sign<<15. 0xFFFF = empty.
// ---------------------------------------------------------------------------
__device__ __forceinline__ void scan_vec(u32x4 w, int vecIdx,
                                         unsigned* s_cnt, uint16_t* s_ent) {
  uint32_t vals[4] = {w[0], w[1], w[2], w[3]};
#pragma unroll
  for (int e = 0; e < 4; ++e) {
    uint32_t u = vals[e];
    if (u != 0u) {  // value is exactly +1.0f or -1.0f
      unsigned slot = atomicAdd(s_cnt, 1u);
      s_ent[slot & 15u] = (uint16_t)(((vecIdx << 2) + e) | ((u >> 31) << 15));
    }
  }
}

__global__ void __launch_bounds__(256) sparsify_pack_kernel(
    const uint32_t* __restrict__ W0a, const uint32_t* __restrict__ W0b,
    const uint32_t* __restrict__ W1a, const uint32_t* __restrict__ W1b,
    const uint32_t* __restrict__ W2a, const uint32_t* __restrict__ W2b,
    const float* __restrict__ x, ull* __restrict__ A0,
    float* __restrict__ out, uint16_t* __restrict__ entries) {
  if (blockIdx.x < 8) {  // pack: binarize x -> per-column batch masks
    int c = blockIdx.x * 256 + threadIdx.x;
    ull m = 0;
#pragma unroll
    for (int b = 0; b < BATCH; ++b)
      m |= (ull)(x[(size_t)b * F_ENC + c] > 0.5f) << b;
    A0[c] = m;
    return;
  }
  if (blockIdx.x == 8) {  // zero d_out for the logits atomicAdd pass
    for (int i = threadIdx.x; i < BATCH * NCLS; i += 256) out[i] = 0.f;
    return;
  }
  int blk = blockIdx.x - EXTRA;
  int m = blk >> 13;               // which matrix (0..5)
  int r = blk & (HID - 1);         // row within matrix
  const uint32_t* Wbase;
  switch (m) {
    case 0: Wbase = W0a; break;
    case 1: Wbase = W0b; break;
    case 2: Wbase = W1a; break;
    case 3: Wbase = W1b; break;
    case 4: Wbase = W2a; break;
    default: Wbase = W2b; break;
  }
  const int cols = (m < 2) ? F_ENC : HID;
  const u32x4* row = (const u32x4*)(Wbase + (size_t)r * cols);

  __shared__ unsigned s_cnt;
  __shared__ uint16_t s_ent[16];
  if (threadIdx.x == 0) s_cnt = 0u;
  __syncthreads();

  if (cols == F_ENC) {  // 2 x dwordx4 per thread
    u32x4 w0 = __builtin_nontemporal_load(row + threadIdx.x);
    u32x4 w1 = __builtin_nontemporal_load(row + threadIdx.x + 256);
    asm volatile("" ::: "memory");
    uint32_t any = w0[0] | w0[1] | w0[2] | w0[3] |
                   w1[0] | w1[1] | w1[2] | w1[3];
    if (any) {
      scan_vec(w0, threadIdx.x, &s_cnt, s_ent);
      scan_vec(w1, threadIdx.x + 256, &s_cnt, s_ent);
    }
  } else {  // 8 x dwordx4 per thread
    u32x4 w[8];
#pragma unroll
    for (int e = 0; e < 8; ++e)
      w[e] = __builtin_nontemporal_load(row + threadIdx.x + (e << 8));
    asm volatile("" ::: "memory");
    uint32_t any = 0;
#pragma unroll
    for (int e = 0; e < 8; ++e) any |= w[e][0] | w[e][1] | w[e][2] | w[e][3];
    if (any) {
#pragma unroll
      for (int e = 0; e < 8; ++e)
        scan_vec(w[e], threadIdx.x + (e << 8), &s_cnt, s_ent);
    }
  }
  __syncthreads();
  if (threadIdx.x < 8) {
    unsigned cnt = s_cnt;
    uint16_t v = (threadIdx.x < cnt) ? s_ent[threadIdx.x] : (uint16_t)0xFFFF;
    entries[(size_t)blk * 8 + threadIdx.x] = v;
  }
}

// ---------------------------------------------------------------------------
// Bit-sliced 4-bit counters over the 64-batch bitmask lanes.
// ---------------------------------------------------------------------------
struct BS4 { ull p0, p1, p2, p3; };

__device__ __forceinline__ void bs_add(BS4& a, ull m) {
  ull c = m, t;
  t = a.p0 ^ c; c &= a.p0; a.p0 = t;
  t = a.p1 ^ c; c &= a.p1; a.p1 = t;
  t = a.p2 ^ c; c &= a.p2; a.p2 = t;
  a.p3 ^= c;  // count <= 8, no overflow
}

// fired = (plus >= minus + 4), per batch bit
__device__ __forceinline__ ull bs_fired(const BS4& A, const BS4& Mn) {
  ull b0 = Mn.p0, b1 = Mn.p1;
  ull carry = Mn.p2;
  ull b2 = ~Mn.p2;
  ull b3 = Mn.p3 ^ carry;
  ull b4 = Mn.p3 & carry;
  ull res = 0, eq = ~0ull;
  eq &= ~b4;  // a4 == 0
  res |= eq & A.p3 & ~b3; eq &= ~(A.p3 ^ b3);
  res |= eq & A.p2 & ~b2; eq &= ~(A.p2 ^ b2);
  res |= eq & A.p1 & ~b1; eq &= ~(A.p1 ^ b1);
  res |= eq & A.p0 & ~b0; eq &= ~(A.p0 ^ b0);
  return res | eq;
}

// Aprev may be a global or an LDS-backed (generic) pointer.
__device__ __forceinline__ ull layer_fire(const uint16_t* __restrict__ ent0,
                                          const uint16_t* __restrict__ ent1,
                                          const ull* Aprev, int h) {
  uint4 p0 = ((const uint4*)ent0)[h];
  uint4 p1 = ((const uint4*)ent1)[h];
  uint32_t wd[8] = {p0.x, p0.y, p0.z, p0.w, p1.x, p1.y, p1.z, p1.w};
  uint16_t es[16];
#pragma unroll
  for (int i = 0; i < 8; ++i) {
    es[2 * i]     = (uint16_t)(wd[i] & 0xFFFFu);
    es[2 * i + 1] = (uint16_t)(wd[i] >> 16);
  }
  ull M[16];
#pragma unroll
  for (int i = 0; i < 16; ++i) {
    int idx = (es[i] == 0xFFFF) ? 0 : (es[i] & 0x1FFF);
    ull v = Aprev[idx];
    M[i] = (es[i] == 0xFFFF) ? 0ull : v;
  }
  ull f = 0;
#pragma unroll
  for (int s = 0; s < 2; ++s) {
    BS4 P{0, 0, 0, 0}, N{0, 0, 0, 0};
#pragma unroll
    for (int i = 0; i < 8; ++i) {
      uint16_t e = es[s * 8 + i];
      ull Mm = M[s * 8 + i];
      ull mp = (e & 0x8000) ? 0ull : Mm;
      ull mn = (e & 0x8000) ? Mm : 0ull;
      bs_add(P, mp);
      bs_add(N, mn);
    }
    f |= bs_fired(P, N);
  }
  return f;
}

// ---------------------------------------------------------------------------
// Kernel 2: fused tail. 256 blocks x 256 threads, 1 block/CU (153 KB LDS).
// Each block recomputes the FULL A1 (gathers from global A0, 16 KB, L1-hot)
// and full A2 (gathers from LDS A1) redundantly, then its own 32-row A3
// slice and the logits for its 32 h-rows. Kills two kernel launches and all
// global A1/A2 roundtrips; block-local __syncthreads replaces stream deps.
// ---------------------------------------------------------------------------
__global__ void __launch_bounds__(256) fused_tail_kernel(
    const uint16_t* __restrict__ entries, const ull* __restrict__ A0,
    const float* __restrict__ O0, const float* __restrict__ O1,
    const float* __restrict__ O2, float* __restrict__ out) {
  __shared__ ull sA1[HID];             // 64 KB
  __shared__ ull sA2[HID];             // 64 KB
  __shared__ float acc[BATCH * NCLS];  // 25.6 KB
  __shared__ ull sA3[32];

  const uint16_t* ent0 = entries + (size_t)0 * HID * 8;
  const uint16_t* ent1 = entries + (size_t)1 * HID * 8;
  const uint16_t* ent2 = entries + (size_t)2 * HID * 8;
  const uint16_t* ent3 = entries + (size_t)3 * HID * 8;
  const uint16_t* ent4 = entries + (size_t)4 * HID * 8;
  const uint16_t* ent5 = entries + (size_t)5 * HID * 8;

  // phase 1: full A1 (global A0 gathers)
#pragma unroll 4
  for (int k = 0; k < 32; ++k) {
    int h = threadIdx.x + k * 256;
    sA1[h] = layer_fire(ent0, ent1, A0, h);
  }
  // zero acc while A1 writes land
  for (int i = threadIdx.x; i < BATCH * NCLS; i += 256) acc[i] = 0.f;
  __syncthreads();

  // phase 2: full A2 (LDS A1 gathers)
#pragma unroll 4
  for (int k = 0; k < 32; ++k) {
    int h = threadIdx.x + k * 256;
    sA2[h] = layer_fire(ent2, ent3, sA1, h);
  }
  __syncthreads();

  // phase 3: own 32-row A3 slice
  const int h0 = blockIdx.x * 32;
  if (threadIdx.x < 32)
    sA3[threadIdx.x] = layer_fire(ent4, ent5, sA2, h0 + threadIdx.x);
  __syncthreads();

  // phase 4: logits for h0..h0+31. Lanes split the 64-batch mask into two
  // 32-bit halves (200 active lanes).
  const int half = threadIdx.x >> 7;  // 0: batches 0-31, 1: batches 32-63
  const int j = threadIdx.x & 127;
  if (j < NCLS) {
    const int bofs = half * 32;
    const int sh = half * 32;
    for (int k = 0; k < 32; ++k) {
      int h = h0 + k;
      uint32_t m1 = (uint32_t)(sA1[h] >> sh);
      uint32_t m2 = (uint32_t)(sA2[h] >> sh);
      uint32_t m3 = (uint32_t)(sA3[k] >> sh);
      if (m1) {
        float o = O0[(size_t)h * NCLS + j];
        do { int b = __builtin_ctz(m1); m1 &= m1 - 1; acc[(b + bofs) * NCLS + j] += o; } while (m1);
      }
      if (m2) {
        float o = O1[(size_t)h * NCLS + j];
        do { int b = __builtin_ctz(m2); m2 &= m2 - 1; acc[(b + bofs) * NCLS + j] += o; } while (m2);
      }
      if (m3) {
        float o = O2[(size_t)h * NCLS + j];
        do { int b = __builtin_ctz(m3); m3 &= m3 - 1; acc[(b + bofs) * NCLS + j] += o; } while (m3);
      }
    }
  }
  __syncthreads();
  for (int i = threadIdx.x; i < BATCH * NCLS; i += 256)
    atomicAdd(&out[i], acc[i]);
}

// ---------------------------------------------------------------------------
extern "C" void kernel_launch(void* const* d_in, const int* in_sizes, int n_in,
                              void* d_out, int out_size, void* d_ws, size_t ws_size,
                              hipStream_t stream) {
  const float*    x   = (const float*)d_in[0];
  const uint32_t* W0a = (const uint32_t*)d_in[1];
  const uint32_t* W0b = (const uint32_t*)d_in[2];
  const uint32_t* W1a = (const uint32_t*)d_in[3];
  const uint32_t* W1b = (const uint32_t*)d_in[4];
  const uint32_t* W2a = (const uint32_t*)d_in[5];
  const uint32_t* W2b = (const uint32_t*)d_in[6];
  const float*    O0  = (const float*)d_in[7];
  const float*    O1  = (const float*)d_in[8];
  const float*    O2  = (const float*)d_in[9];
  float* out = (float*)d_out;
  char*  ws  = (char*)d_ws;

  // ws layout (all written before read every call):
  ull* A0 = (ull*)(ws);                          // 16384 B
  uint16_t* entries = (uint16_t*)(ws + 16384);   // 786432 B

  sparsify_pack_kernel<<<EXTRA + NMAT * HID, 256, 0, stream>>>(
      W0a, W0b, W1a, W1b, W2a, W2b, x, A0, out, entries);
  fused_tail_kernel<<<HID / 32, 256, 0, stream>>>(entries, A0, O0, O1, O2,
                                                  out);
}

// Round 10
// 213.544 us; speedup vs baseline: 11.6544x; 1.4304x over previous
//
#include <hip/hip_runtime.h>
#include <stdint.h>

#define BATCH 64
#define F_ENC 2048
#define HID 8192
#define NCLS 100
#define NMAT 6
#define EXTRA 9  // 8 pack blocks + 1 out-zero block, prepended so they run first

typedef unsigned long long ull;
typedef uint32_t u32x4 __attribute__((ext_vector_type(4)));

// ---------------------------------------------------------------------------
// Kernel 1: sparsify (proven 196 us = read roofline) with pack + d_out
// zeroing fused in as EXTRA leading blocks.
// Entry: uint16 = col (13b) | sign<<15. 0xFFFF = empty.
// ---------------------------------------------------------------------------
__device__ __forceinline__ void scan_vec(u32x4 w, int vecIdx,
                                         unsigned* s_cnt, uint16_t* s_ent) {
  uint32_t vals[4] = {w[0], w[1], w[2], w[3]};
#pragma unroll
  for (int e = 0; e < 4; ++e) {
    uint32_t u = vals[e];
    if (u != 0u) {  // value is exactly +1.0f or -1.0f
      unsigned slot = atomicAdd(s_cnt, 1u);
      s_ent[slot & 15u] = (uint16_t)(((vecIdx << 2) + e) | ((u >> 31) << 15));
    }
  }
}

__global__ void __launch_bounds__(256) sparsify_pack_kernel(
    const uint32_t* __restrict__ W0a, const uint32_t* __restrict__ W0b,
    const uint32_t* __restrict__ W1a, const uint32_t* __restrict__ W1b,
    const uint32_t* __restrict__ W2a, const uint32_t* __restrict__ W2b,
    const float* __restrict__ x, ull* __restrict__ A0,
    float* __restrict__ out, uint16_t* __restrict__ entries) {
  if (blockIdx.x < 8) {  // pack: binarize x -> per-column batch masks
    int c = blockIdx.x * 256 + threadIdx.x;
    ull m = 0;
#pragma unroll
    for (int b = 0; b < BATCH; ++b)
      m |= (ull)(x[(size_t)b * F_ENC + c] > 0.5f) << b;
    A0[c] = m;
    return;
  }
  if (blockIdx.x == 8) {  // zero d_out for the logits atomicAdd pass
    for (int i = threadIdx.x; i < BATCH * NCLS; i += 256) out[i] = 0.f;
    return;
  }
  int blk = blockIdx.x - EXTRA;
  int m = blk >> 13;               // which matrix (0..5)
  int r = blk & (HID - 1);         // row within matrix
  const uint32_t* Wbase;
  switch (m) {
    case 0: Wbase = W0a; break;
    case 1: Wbase = W0b; break;
    case 2: Wbase = W1a; break;
    case 3: Wbase = W1b; break;
    case 4: Wbase = W2a; break;
    default: Wbase = W2b; break;
  }
  const int cols = (m < 2) ? F_ENC : HID;
  const u32x4* row = (const u32x4*)(Wbase + (size_t)r * cols);

  __shared__ unsigned s_cnt;
  __shared__ uint16_t s_ent[16];
  if (threadIdx.x == 0) s_cnt = 0u;
  __syncthreads();

  if (cols == F_ENC) {  // 2 x dwordx4 per thread
    u32x4 w0 = __builtin_nontemporal_load(row + threadIdx.x);
    u32x4 w1 = __builtin_nontemporal_load(row + threadIdx.x + 256);
    asm volatile("" ::: "memory");
    uint32_t any = w0[0] | w0[1] | w0[2] | w0[3] |
                   w1[0] | w1[1] | w1[2] | w1[3];
    if (any) {
      scan_vec(w0, threadIdx.x, &s_cnt, s_ent);
      scan_vec(w1, threadIdx.x + 256, &s_cnt, s_ent);
    }
  } else {  // 8 x dwordx4 per thread
    u32x4 w[8];
#pragma unroll
    for (int e = 0; e < 8; ++e)
      w[e] = __builtin_nontemporal_load(row + threadIdx.x + (e << 8));
    asm volatile("" ::: "memory");
    uint32_t any = 0;
#pragma unroll
    for (int e = 0; e < 8; ++e) any |= w[e][0] | w[e][1] | w[e][2] | w[e][3];
    if (any) {
#pragma unroll
      for (int e = 0; e < 8; ++e)
        scan_vec(w[e], threadIdx.x + (e << 8), &s_cnt, s_ent);
    }
  }
  __syncthreads();
  if (threadIdx.x < 8) {
    unsigned cnt = s_cnt;
    uint16_t v = (threadIdx.x < cnt) ? s_ent[threadIdx.x] : (uint16_t)0xFFFF;
    entries[(size_t)blk * 8 + threadIdx.x] = v;
  }
}

// ---------------------------------------------------------------------------
// Bit-sliced 4-bit counters over the 64-batch bitmask lanes.
// ---------------------------------------------------------------------------
struct BS4 { ull p0, p1, p2, p3; };

__device__ __forceinline__ void bs_add(BS4& a, ull m) {
  ull c = m, t;
  t = a.p0 ^ c; c &= a.p0; a.p0 = t;
  t = a.p1 ^ c; c &= a.p1; a.p1 = t;
  t = a.p2 ^ c; c &= a.p2; a.p2 = t;
  a.p3 ^= c;  // count <= 8, no overflow
}

// fired = (plus >= minus + 4), per batch bit
__device__ __forceinline__ ull bs_fired(const BS4& A, const BS4& Mn) {
  ull b0 = Mn.p0, b1 = Mn.p1;
  ull carry = Mn.p2;
  ull b2 = ~Mn.p2;
  ull b3 = Mn.p3 ^ carry;
  ull b4 = Mn.p3 & carry;
  ull res = 0, eq = ~0ull;
  eq &= ~b4;  // a4 == 0
  res |= eq & A.p3 & ~b3; eq &= ~(A.p3 ^ b3);
  res |= eq & A.p2 & ~b2; eq &= ~(A.p2 ^ b2);
  res |= eq & A.p1 & ~b1; eq &= ~(A.p1 ^ b1);
  res |= eq & A.p0 & ~b0; eq &= ~(A.p0 ^ b0);
  return res | eq;
}

__device__ __forceinline__ ull layer_fire(const uint16_t* __restrict__ ent0,
                                          const uint16_t* __restrict__ ent1,
                                          const ull* __restrict__ Aprev,
                                          int h) {
  uint4 p0 = ((const uint4*)ent0)[h];
  uint4 p1 = ((const uint4*)ent1)[h];
  uint32_t wd[8] = {p0.x, p0.y, p0.z, p0.w, p1.x, p1.y, p1.z, p1.w};
  uint16_t es[16];
#pragma unroll
  for (int i = 0; i < 8; ++i) {
    es[2 * i]     = (uint16_t)(wd[i] & 0xFFFFu);
    es[2 * i + 1] = (uint16_t)(wd[i] >> 16);
  }
  ull M[16];
#pragma unroll
  for (int i = 0; i < 16; ++i) {
    int idx = (es[i] == 0xFFFF) ? 0 : (es[i] & 0x1FFF);
    ull v = Aprev[idx];
    M[i] = (es[i] == 0xFFFF) ? 0ull : v;
  }
  ull f = 0;
#pragma unroll
  for (int s = 0; s < 2; ++s) {
    BS4 P{0, 0, 0, 0}, N{0, 0, 0, 0};
#pragma unroll
    for (int i = 0; i < 8; ++i) {
      uint16_t e = es[s * 8 + i];
      ull Mm = M[s * 8 + i];
      ull mp = (e & 0x8000) ? 0ull : Mm;
      ull mn = (e & 0x8000) ? Mm : 0ull;
      bs_add(P, mp);
      bs_add(N, mn);
    }
    f |= bs_fired(P, N);
  }
  return f;
}

// ---------------------------------------------------------------------------
// Kernel 2: one layer (A_prev -> A_next), 32 blocks x 256 threads.
// ---------------------------------------------------------------------------
__global__ void __launch_bounds__(256) layer_kernel(
    const uint16_t* __restrict__ ent0, const uint16_t* __restrict__ ent1,
    const ull* __restrict__ Aprev, ull* __restrict__ Anext) {
  int h = blockIdx.x * blockDim.x + threadIdx.x;
  if (h >= HID) return;
  Anext[h] = layer_fire(ent0, ent1, Aprev, h);
}

// ---------------------------------------------------------------------------
// Kernel 3: layer3 + logits fused. Each block owns 32 h-rows: computes its
// A3 rows into LDS (A2 is globally complete), then accumulates logits for
// all three layers. 256 threads: lanes split the 64-batch mask into two
// 32-bit halves (200 active lanes). One atomicAdd pass into zeroed d_out.
// ---------------------------------------------------------------------------
__global__ void __launch_bounds__(256) logits_kernel(
    const uint16_t* __restrict__ ent4, const uint16_t* __restrict__ ent5,
    const ull* __restrict__ A1, const ull* __restrict__ A2,
    const float* __restrict__ O0, const float* __restrict__ O1,
    const float* __restrict__ O2, float* __restrict__ out) {
  __shared__ float acc[BATCH * NCLS];  // 25.6 KB
  __shared__ ull sA3[32];
  const int h0 = blockIdx.x * 32;
  if (threadIdx.x < 32)
    sA3[threadIdx.x] = layer_fire(ent4, ent5, A2, h0 + threadIdx.x);
  for (int i = threadIdx.x; i < BATCH * NCLS; i += 256) acc[i] = 0.f;
  __syncthreads();
  const int half = threadIdx.x >> 7;  // 0: batches 0-31, 1: batches 32-63
  const int j = threadIdx.x & 127;
  if (j < NCLS) {
    const int bofs = half * 32;
    const int sh = half * 32;
    for (int k = 0; k < 32; ++k) {
      int h = h0 + k;
      uint32_t m1 = (uint32_t)(A1[h] >> sh);
      uint32_t m2 = (uint32_t)(A2[h] >> sh);
      uint32_t m3 = (uint32_t)(sA3[k] >> sh);
      if (m1) {
        float o = O0[(size_t)h * NCLS + j];
        do { int b = __builtin_ctz(m1); m1 &= m1 - 1; acc[(b + bofs) * NCLS + j] += o; } while (m1);
      }
      if (m2) {
        float o = O1[(size_t)h * NCLS + j];
        do { int b = __builtin_ctz(m2); m2 &= m2 - 1; acc[(b + bofs) * NCLS + j] += o; } while (m2);
      }
      if (m3) {
        float o = O2[(size_t)h * NCLS + j];
        do { int b = __builtin_ctz(m3); m3 &= m3 - 1; acc[(b + bofs) * NCLS + j] += o; } while (m3);
      }
    }
  }
  __syncthreads();
  for (int i = threadIdx.x; i < BATCH * NCLS; i += 256)
    atomicAdd(&out[i], acc[i]);
}

// ---------------------------------------------------------------------------
extern "C" void kernel_launch(void* const* d_in, const int* in_sizes, int n_in,
                              void* d_out, int out_size, void* d_ws, size_t ws_size,
                              hipStream_t stream) {
  const float*    x   = (const float*)d_in[0];
  const uint32_t* W0a = (const uint32_t*)d_in[1];
  const uint32_t* W0b = (const uint32_t*)d_in[2];
  const uint32_t* W1a = (const uint32_t*)d_in[3];
  const uint32_t* W1b = (const uint32_t*)d_in[4];
  const uint32_t* W2a = (const uint32_t*)d_in[5];
  const uint32_t* W2b = (const uint32_t*)d_in[6];
  const float*    O0  = (const float*)d_in[7];
  const float*    O1  = (const float*)d_in[8];
  const float*    O2  = (const float*)d_in[9];
  float* out = (float*)d_out;
  char*  ws  = (char*)d_ws;

  // ws layout (all written before read every call; <1 MB total):
  ull* A0 = (ull*)(ws);                          // 2048*8  = 16384 B
  ull* A1 = (ull*)(ws + 16384);                  // 8192*8  = 65536 B
  ull* A2 = (ull*)(ws + 16384 + 65536);
  uint16_t* entries = (uint16_t*)(ws + 16384 + 2 * 65536);  // 786432 B

  sparsify_pack_kernel<<<EXTRA + NMAT * HID, 256, 0, stream>>>(
      W0a, W0b, W1a, W1b, W2a, W2b, x, A0, out, entries);
  layer_kernel<<<HID / 256, 256, 0, stream>>>(
      entries + (size_t)0 * HID * 8, entries + (size_t)1 * HID * 8, A0, A1);
  layer_kernel<<<HID / 256, 256, 0, stream>>>(
      entries + (size_t)2 * HID * 8, entries + (size_t)3 * HID * 8, A1, A2);
  logits_kernel<<<HID / 32, 256, 0, stream>>>(
      entries + (size_t)4 * HID * 8, entries + (size_t)5 * HID * 8,
      A1, A2, O0, O1, O2, out);
}